// Round 1
// baseline (607.556 us; speedup 1.0000x reference)
//
#include <hip/hip_runtime.h>
#include <math.h>

#define FIN 78
#define HD1 512
#define D2  128

__device__ __forceinline__ float lrelu(float x) { return x > 0.f ? x : 0.2f * x; }
__device__ __forceinline__ float elu(float x)   { return x > 0.f ? x : expf(x) - 1.f; }

// ---------- layer-1 input GEMM: x[N,78] @ {Wl1,Wr1}[78,512] + bias ----------
__global__ void gemm1_k(const float* __restrict__ x,
                        const float* __restrict__ Wl, const float* __restrict__ bl,
                        const float* __restrict__ Wr, const float* __restrict__ br,
                        float* __restrict__ xl, float* __restrict__ xr, int N)
{
    __shared__ float xs[4][FIN];
    int row0 = blockIdx.x * 4;
    int t = threadIdx.x;
    for (int idx = t; idx < 4 * FIN; idx += 256) {
        int r = idx / FIN, k = idx - r * FIN;
        int row = row0 + r;
        xs[r][k] = (row < N) ? x[(size_t)row * FIN + k] : 0.f;
    }
    __syncthreads();
    for (int i = 0; i < 4; ++i) {
        int j = t + i * 256;                 // 0..1023
        const float* W; float* out; int col; float b;
        if (j < HD1) { W = Wl; out = xl; col = j;       b = bl[col]; }
        else         { W = Wr; out = xr; col = j - HD1; b = br[col]; }
        float a0 = b, a1 = b, a2 = b, a3 = b;
        for (int k = 0; k < FIN; ++k) {
            float w = W[k * HD1 + col];
            a0 += xs[0][k] * w; a1 += xs[1][k] * w;
            a2 += xs[2][k] * w; a3 += xs[3][k] * w;
        }
        if (row0 + 0 < N) out[(size_t)(row0 + 0) * HD1 + col] = a0;
        if (row0 + 1 < N) out[(size_t)(row0 + 1) * HD1 + col] = a1;
        if (row0 + 2 < N) out[(size_t)(row0 + 2) * HD1 + col] = a2;
        if (row0 + 3 < N) out[(size_t)(row0 + 3) * HD1 + col] = a3;
    }
}

// ---------- layer-2 input GEMM: h1[N,512] @ {Wl2,Wr2}[512,128] + bias ----------
__global__ void gemm2_k(const float* __restrict__ h,
                        const float* __restrict__ Wl, const float* __restrict__ bl,
                        const float* __restrict__ Wr, const float* __restrict__ br,
                        float* __restrict__ xl, float* __restrict__ xr, int N)
{
    __shared__ float hs[8][HD1];
    int row0 = blockIdx.x * 8;
    int t = threadIdx.x;
    for (int idx = t; idx < 8 * HD1; idx += 256) {
        int r = idx >> 9, k = idx & 511;
        int row = row0 + r;
        hs[r][k] = (row < N) ? h[(size_t)row * HD1 + k] : 0.f;
    }
    __syncthreads();
    const float* W; float* out; int col; float b;
    if (t < D2) { W = Wl; out = xl; col = t;      b = bl[col]; }
    else        { W = Wr; out = xr; col = t - D2; b = br[col]; }
    float acc[8];
#pragma unroll
    for (int r = 0; r < 8; ++r) acc[r] = b;
    for (int k = 0; k < HD1; ++k) {
        float w = W[k * D2 + col];
#pragma unroll
        for (int r = 0; r < 8; ++r) acc[r] += hs[r][k] * w;
    }
    for (int r = 0; r < 8; ++r) {
        int row = row0 + r;
        if (row < N) out[(size_t)row * D2 + col] = acc[r];
    }
}

// ---------- CSR build over destination nodes ----------
__global__ void count_k(const int* __restrict__ ei, int E, int Etot, int* __restrict__ counts)
{
    int e = blockIdx.x * 256 + threadIdx.x;
    if (e >= Etot) return;
    int dst = (e < E) ? ei[E + e] : (e - E);
    atomicAdd(&counts[dst], 1);
}

__global__ void scan_k(const int* __restrict__ counts, int* __restrict__ row_ptr,
                       int* __restrict__ offs, int N)
{
    __shared__ int sdata[1024];
    int t = threadIdx.x;
    int chunk = (N + 1023) / 1024;
    int lo = t * chunk, hi = min(lo + chunk, N);
    int p = 0;
    for (int i = lo; i < hi; ++i) p += counts[i];
    sdata[t] = p;
    __syncthreads();
    for (int off = 1; off < 1024; off <<= 1) {
        int v = (t >= off) ? sdata[t - off] : 0;
        __syncthreads();
        sdata[t] += v;
        __syncthreads();
    }
    int run = sdata[t] - p;   // exclusive prefix
    for (int i = lo; i < hi; ++i) { row_ptr[i] = run; offs[i] = run; run += counts[i]; }
    if (t == 1023) row_ptr[N] = sdata[1023];
}

__global__ void scatter_k(const int* __restrict__ ei, int E, int Etot,
                          int* __restrict__ offs, int* __restrict__ csr_src,
                          int* __restrict__ csr_eid)
{
    int e = blockIdx.x * 256 + threadIdx.x;
    if (e >= Etot) return;
    int src, dst;
    if (e < E) { src = ei[e]; dst = ei[E + e]; } else { src = dst = e - E; }
    int pos = atomicAdd(&offs[dst], 1);
    csr_src[pos] = src;
    csr_eid[pos] = e;
}

// ---------- layer-1 edge scores: 1 wave = 1 edge, 4 heads via 16-lane groups ----------
__global__ void score1_k(const int* __restrict__ ei, int E, int Etot,
                         const float* __restrict__ xl, const float* __restrict__ xr,
                         const float* __restrict__ att, float* __restrict__ logits)
{
    int e = blockIdx.x * 4 + (threadIdx.x >> 6);
    if (e >= Etot) return;
    int lane = threadIdx.x & 63;
    int src, dst;
    if (e < E) { src = ei[e]; dst = ei[E + e]; } else { src = dst = e - E; }
    int c0 = lane * 8;                              // head = lane/16
    const float4* pa = reinterpret_cast<const float4*>(xl + (size_t)src * HD1 + c0);
    const float4* pb = reinterpret_cast<const float4*>(xr + (size_t)dst * HD1 + c0);
    const float4* pt = reinterpret_cast<const float4*>(att + c0);
    float4 a0 = pa[0], a1 = pa[1];
    float4 b0 = pb[0], b1 = pb[1];
    float4 t0 = pt[0], t1 = pt[1];
    float s = t0.x * lrelu(a0.x + b0.x) + t0.y * lrelu(a0.y + b0.y)
            + t0.z * lrelu(a0.z + b0.z) + t0.w * lrelu(a0.w + b0.w)
            + t1.x * lrelu(a1.x + b1.x) + t1.y * lrelu(a1.y + b1.y)
            + t1.z * lrelu(a1.z + b1.z) + t1.w * lrelu(a1.w + b1.w);
    for (int off = 1; off < 16; off <<= 1) s += __shfl_xor(s, off);
    if ((lane & 15) == 0) logits[(size_t)e * 4 + (lane >> 4)] = s;
}

// ---------- layer-1 softmax + aggregate + bias + ELU, one node per block ----------
__global__ void agg1_k(const int* __restrict__ row_ptr, const int* __restrict__ csr_src,
                       const int* __restrict__ csr_eid, const float* __restrict__ logits,
                       const float* __restrict__ xl, const float* __restrict__ bias,
                       float* __restrict__ out)
{
    __shared__ float smax[4], sinv[4];
    __shared__ int   s_src[64];
    __shared__ float s_alpha[256];
    int v = blockIdx.x;
    int t = threadIdx.x;
    int base = row_ptr[v], deg = row_ptr[v + 1] - base;
    int w = t >> 6, lane = t & 63;
    // per-head max
    float m = -INFINITY;
    for (int i = lane; i < deg; i += 64)
        m = fmaxf(m, logits[(size_t)csr_eid[base + i] * 4 + w]);
    for (int off = 1; off < 64; off <<= 1) m = fmaxf(m, __shfl_xor(m, off));
    // per-head sum
    float s = 0.f;
    for (int i = lane; i < deg; i += 64)
        s += expf(logits[(size_t)csr_eid[base + i] * 4 + w] - m);
    for (int off = 1; off < 64; off <<= 1) s += __shfl_xor(s, off);
    if (lane == 0) { smax[w] = m; sinv[w] = 1.f / s; }
    __syncthreads();
    int h0 = t >> 7;                 // head of channel t (0/1); channel t+256 -> h0+2
    float acc0 = 0.f, acc1 = 0.f;
    for (int c0 = 0; c0 < deg; c0 += 64) {
        int nc = min(64, deg - c0);
        if (t < nc) s_src[t] = csr_src[base + c0 + t];
        if (t < nc * 4) {
            int i = t >> 2, h = t & 3;
            float l = logits[(size_t)csr_eid[base + c0 + i] * 4 + h];
            s_alpha[t] = expf(l - smax[h]) * sinv[h];
        }
        __syncthreads();
        for (int i = 0; i < nc; ++i) {
            const float* xs = xl + (size_t)s_src[i] * HD1;
            acc0 += s_alpha[i * 4 + h0]     * xs[t];
            acc1 += s_alpha[i * 4 + h0 + 2] * xs[t + 256];
        }
        __syncthreads();
    }
    out[(size_t)v * HD1 + t]       = elu(acc0 + bias[t]);
    out[(size_t)v * HD1 + t + 256] = elu(acc1 + bias[t + 256]);
}

// ---------- layer-2 edge scores: 1 wave = 1 edge, single head ----------
__global__ void score2_k(const int* __restrict__ ei, int E, int Etot,
                         const float* __restrict__ xl, const float* __restrict__ xr,
                         const float* __restrict__ att, float* __restrict__ logits)
{
    int e = blockIdx.x * 4 + (threadIdx.x >> 6);
    if (e >= Etot) return;
    int lane = threadIdx.x & 63;
    int src, dst;
    if (e < E) { src = ei[e]; dst = ei[E + e]; } else { src = dst = e - E; }
    int c0 = lane * 2;
    const float2* pa = reinterpret_cast<const float2*>(xl + (size_t)src * D2 + c0);
    const float2* pb = reinterpret_cast<const float2*>(xr + (size_t)dst * D2 + c0);
    const float2* pt = reinterpret_cast<const float2*>(att + c0);
    float2 a = pa[0], b = pb[0], tt = pt[0];
    float s = tt.x * lrelu(a.x + b.x) + tt.y * lrelu(a.y + b.y);
    for (int off = 1; off < 64; off <<= 1) s += __shfl_xor(s, off);
    if (lane == 0) logits[e] = s;
}

// ---------- layer-2 softmax + aggregate + bias + ELU ----------
__global__ void agg2_k(const int* __restrict__ row_ptr, const int* __restrict__ csr_src,
                       const int* __restrict__ csr_eid, const float* __restrict__ logits,
                       const float* __restrict__ xl, const float* __restrict__ bias,
                       float* __restrict__ out)
{
    __shared__ float red[128];
    __shared__ int   s_src[128];
    __shared__ float s_alpha[128];
    int v = blockIdx.x;
    int t = threadIdx.x;
    int base = row_ptr[v], deg = row_ptr[v + 1] - base;
    float m = -INFINITY;
    for (int i = t; i < deg; i += 128) m = fmaxf(m, logits[csr_eid[base + i]]);
    red[t] = m; __syncthreads();
    for (int s = 64; s > 0; s >>= 1) { if (t < s) red[t] = fmaxf(red[t], red[t + s]); __syncthreads(); }
    float M = red[0]; __syncthreads();
    float sm = 0.f;
    for (int i = t; i < deg; i += 128) sm += expf(logits[csr_eid[base + i]] - M);
    red[t] = sm; __syncthreads();
    for (int s = 64; s > 0; s >>= 1) { if (t < s) red[t] += red[t + s]; __syncthreads(); }
    float S = red[0]; __syncthreads();
    float acc = 0.f;
    for (int c0 = 0; c0 < deg; c0 += 128) {
        int nc = min(128, deg - c0);
        if (t < nc) {
            int j = base + c0 + t;
            s_src[t]   = csr_src[j];
            s_alpha[t] = expf(logits[csr_eid[j]] - M);
        }
        __syncthreads();
        for (int i = 0; i < nc; ++i)
            acc += s_alpha[i] * xl[(size_t)s_src[i] * D2 + t];
        __syncthreads();
    }
    out[(size_t)v * D2 + t] = elu(acc / S + bias[t]);
}

// ---------- global mean pool ----------
__global__ void pool_k(const int* __restrict__ batch, const float* __restrict__ h,
                       float* __restrict__ out, float* __restrict__ cnt, int N)
{
    int idx = blockIdx.x * 256 + threadIdx.x;
    if (idx >= N * D2) return;
    int v = idx >> 7, c = idx & 127;
    int g = batch[v];
    atomicAdd(&out[(size_t)g * D2 + c], h[idx]);
    if (c == 0) atomicAdd(&cnt[g], 1.0f);
}

__global__ void pooldiv_k(float* __restrict__ out, const float* __restrict__ cnt, int total)
{
    int idx = blockIdx.x * 256 + threadIdx.x;
    if (idx >= total) return;
    out[idx] /= fmaxf(cnt[idx >> 7], 1.0f);
}

extern "C" void kernel_launch(void* const* d_in, const int* in_sizes, int n_in,
                              void* d_out, int out_size, void* d_ws, size_t ws_size,
                              hipStream_t stream)
{
    const float* x    = (const float*)d_in[0];
    const int*   ei   = (const int*)d_in[1];
    const int*   batch= (const int*)d_in[2];
    const float* Wl1  = (const float*)d_in[3];
    const float* bl1  = (const float*)d_in[4];
    const float* Wr1  = (const float*)d_in[5];
    const float* br1  = (const float*)d_in[6];
    const float* att1 = (const float*)d_in[7];
    const float* bias1= (const float*)d_in[8];
    const float* Wl2  = (const float*)d_in[9];
    const float* bl2  = (const float*)d_in[10];
    const float* Wr2  = (const float*)d_in[11];
    const float* br2  = (const float*)d_in[12];
    const float* att2 = (const float*)d_in[13];
    const float* bias2= (const float*)d_in[14];
    float* out = (float*)d_out;

    int N    = in_sizes[2];          // batch vector length = nodes
    int E    = in_sizes[1] / 2;      // directed edges (before self-loops)
    int Etot = E + N;
    int G    = out_size / D2;

    char* ws = (char*)d_ws;
    size_t off = 0;
    auto alloc = [&](size_t bytes) -> void* {
        void* p = ws + off;
        off = (off + bytes + 255) & ~(size_t)255;
        return p;
    };
    float* xl1     = (float*)alloc((size_t)N * HD1 * 4);
    float* xr1     = (float*)alloc((size_t)N * HD1 * 4);  // layer-2 buffers alias here later
    float* h1      = (float*)alloc((size_t)N * HD1 * 4);
    float* logits1 = (float*)alloc((size_t)Etot * 4 * 4);
    int*   counts  = (int*)alloc((size_t)(N + 1) * 4);
    int*   offs    = (int*)alloc((size_t)(N + 1) * 4);
    int*   row_ptr = (int*)alloc((size_t)(N + 1) * 4);
    int*   csr_src = (int*)alloc((size_t)Etot * 4);
    int*   csr_eid = (int*)alloc((size_t)Etot * 4);
    float* poolcnt = (float*)alloc((size_t)(G + 1) * 4);
    // layer-2 aliases inside xr1 (xr1 dead after score1_k):
    float* xl2     = xr1;
    float* xr2     = xr1 + (size_t)N * D2;
    float* h2      = xr1 + (size_t)2 * N * D2;
    float* logits2 = xr1 + (size_t)3 * N * D2;

    hipMemsetAsync(counts, 0, (size_t)(N + 1) * 4, stream);
    gemm1_k<<<(N + 3) / 4, 256, 0, stream>>>(x, Wl1, bl1, Wr1, br1, xl1, xr1, N);
    count_k<<<(Etot + 255) / 256, 256, 0, stream>>>(ei, E, Etot, counts);
    scan_k<<<1, 1024, 0, stream>>>(counts, row_ptr, offs, N);
    scatter_k<<<(Etot + 255) / 256, 256, 0, stream>>>(ei, E, Etot, offs, csr_src, csr_eid);
    score1_k<<<(Etot + 3) / 4, 256, 0, stream>>>(ei, E, Etot, xl1, xr1, att1, logits1);
    agg1_k<<<N, 256, 0, stream>>>(row_ptr, csr_src, csr_eid, logits1, xl1, bias1, h1);
    gemm2_k<<<(N + 7) / 8, 256, 0, stream>>>(h1, Wl2, bl2, Wr2, br2, xl2, xr2, N);
    score2_k<<<(Etot + 3) / 4, 256, 0, stream>>>(ei, E, Etot, xl2, xr2, att2, logits2);
    agg2_k<<<N, 128, 0, stream>>>(row_ptr, csr_src, csr_eid, logits2, xl2, bias2, h2);
    hipMemsetAsync(out, 0, (size_t)out_size * 4, stream);
    hipMemsetAsync(poolcnt, 0, (size_t)G * 4, stream);
    pool_k<<<((N * D2) + 255) / 256, 256, 0, stream>>>(batch, h2, out, poolcnt, N);
    pooldiv_k<<<(out_size + 255) / 256, 256, 0, stream>>>(out, poolcnt, out_size);
}